// Round 1
// baseline (144.386 us; speedup 1.0000x reference)
//
#include <hip/hip_runtime.h>
#include <math.h>

#define L      4096
#define LOG2L  12
#define NT     256
#define TWO_PI 6.28318530717958647692f

// In-place radix-2 DIT FFT over LDS arrays re/im (length L), natural-order
// input, natural-order output. sign = -1 forward, +1 inverse (unscaled).
__device__ inline void fft_lds(float* re, float* im, int tid, float sign) {
    // Bit-reversal permutation (disjoint swap pairs; owner is lower index).
    for (int idx = tid; idx < L; idx += NT) {
        int r = (int)(__brev((unsigned)idx) >> (32 - LOG2L));
        if (r > idx) {
            float tr = re[idx], ti = im[idx];
            re[idx] = re[r]; im[idx] = im[r];
            re[r] = tr;      im[r] = ti;
        }
    }
    __syncthreads();
    for (int s = 1; s <= LOG2L; ++s) {
        const int half = 1 << (s - 1);
        const float angScale = sign * TWO_PI / (float)(1 << s);
        for (int j = tid; j < (L >> 1); j += NT) {
            int blk = j >> (s - 1);
            int pos = j & (half - 1);
            int i0  = (blk << s) + pos;
            int i1  = i0 + half;
            float wr, wi;
            __sincosf(angScale * (float)pos, &wi, &wr);
            float xr = re[i1], xi = im[i1];
            float tr = wr * xr - wi * xi;
            float ti = wr * xi + wi * xr;
            float ur = re[i0], ui = im[i0];
            re[i0] = ur + tr; im[i0] = ui + ti;
            re[i1] = ur - tr; im[i1] = ui - ti;
        }
        __syncthreads();
    }
}

// Kernel 1: per (t,c) row — zero-pad 62x62 -> 64x64, forward FFT(4096),
// threshold |Re|<10 -> 0, store complex spectrum to workspace.
__global__ __launch_bounds__(NT) void fwd_fft_kernel(const float* __restrict__ x,
                                                     float2* __restrict__ X) {
    __shared__ float re[L];
    __shared__ float im[L];
    const int tc  = blockIdx.x;            // t*16 + c
    const int tid = threadIdx.x;
    const float* xrow = x + (size_t)tc * 62 * 62;
    for (int idx = tid; idx < L; idx += NT) {
        int r = idx >> 6, s = idx & 63;
        float v = 0.0f;
        if (r >= 1 && r <= 62 && s >= 1 && s <= 62)
            v = xrow[(r - 1) * 62 + (s - 1)];
        re[idx] = v;
        im[idx] = 0.0f;
    }
    __syncthreads();
    fft_lds(re, im, tid, -1.0f);
    float2* Xrow = X + (size_t)tc * L;
    for (int k = tid; k < L; k += NT) {
        float rr = re[k], ii = im[k];
        if (fabsf(rr) < 10.0f) { rr = 0.0f; ii = 0.0f; }
        Xrow[k] = make_float2(rr, ii);
    }
}

// Kernel 2: per (t,o) — S[k] = sum_c X[t,c,k] * conj(FFT(Wp)[o,c,k]) with
// conj(Wf) built from 9 twiddles u^i v^j; inverse FFT; crop 62x62; +bias.
__global__ __launch_bounds__(NT) void conv_ifft_kernel(const float2* __restrict__ X,
                                                       const float* __restrict__ W,
                                                       const float* __restrict__ b,
                                                       float* __restrict__ out) {
    __shared__ float re[L];
    __shared__ float im[L];
    __shared__ float Wsh[16 * 9];
    const int bid = blockIdx.x;
    const int t   = bid >> 5;
    const int o   = bid & 31;
    const int tid = threadIdx.x;
    if (tid < 144) Wsh[tid] = W[o * 144 + tid];
    __syncthreads();

    for (int k = tid; k < L; k += NT) {
        // u = exp(+2πi k/64), v = exp(+2πi k/4096); tw[i*3+j] = u^i v^j
        float v1r, v1i, u1r, u1i;
        __sincosf(TWO_PI * (float)k * (1.0f / 4096.0f), &v1i, &v1r);
        __sincosf(TWO_PI * (float)(k & 63) * (1.0f / 64.0f), &u1i, &u1r);
        float v2r = v1r * v1r - v1i * v1i, v2i = 2.0f * v1r * v1i;
        float u2r = u1r * u1r - u1i * u1i, u2i = 2.0f * u1r * u1i;
        float twr[9], twi[9];
        twr[0] = 1.0f;                twi[0] = 0.0f;
        twr[1] = v1r;                 twi[1] = v1i;
        twr[2] = v2r;                 twi[2] = v2i;
        twr[3] = u1r;                 twi[3] = u1i;
        twr[4] = u1r*v1r - u1i*v1i;   twi[4] = u1r*v1i + u1i*v1r;
        twr[5] = u1r*v2r - u1i*v2i;   twi[5] = u1r*v2i + u1i*v2r;
        twr[6] = u2r;                 twi[6] = u2i;
        twr[7] = u2r*v1r - u2i*v1i;   twi[7] = u2r*v1i + u2i*v1r;
        twr[8] = u2r*v2r - u2i*v2i;   twi[8] = u2r*v2i + u2i*v2r;

        float Sr = 0.0f, Si = 0.0f;
        const float2* Xt = X + (size_t)t * 16 * L + k;
        #pragma unroll
        for (int c = 0; c < 16; ++c) {
            float2 xc = Xt[(size_t)c * L];
            const float* wc = &Wsh[c * 9];
            float hr = 0.0f, hi = 0.0f;
            #pragma unroll
            for (int m = 0; m < 9; ++m) {
                hr += wc[m] * twr[m];
                hi += wc[m] * twi[m];
            }
            Sr += xc.x * hr - xc.y * hi;
            Si += xc.x * hi + xc.y * hr;
        }
        re[k] = Sr;
        im[k] = Si;
    }
    __syncthreads();
    fft_lds(re, im, tid, +1.0f);

    const float bias = b[o];
    float* orow = out + (size_t)(t * 32 + o) * 62 * 62;
    for (int idx = tid; idx < L; idx += NT) {
        int r = idx >> 6, s = idx & 63;
        if (r < 62 && s < 62)
            orow[r * 62 + s] = re[idx] * (1.0f / 4096.0f) + bias;
    }
}

extern "C" void kernel_launch(void* const* d_in, const int* in_sizes, int n_in,
                              void* d_out, int out_size, void* d_ws, size_t ws_size,
                              hipStream_t stream) {
    const float* x = (const float*)d_in[0];   // (8,16,62,62) f32
    const float* W = (const float*)d_in[1];   // (32,16,3,3)  f32
    const float* b = (const float*)d_in[2];   // (32,)        f32
    float* out = (float*)d_out;               // (8,32,62,62) f32
    float2* X = (float2*)d_ws;                // 128*4096 complex = 4 MB

    fwd_fft_kernel<<<dim3(128), dim3(NT), 0, stream>>>(x, X);
    conv_ifft_kernel<<<dim3(256), dim3(NT), 0, stream>>>(X, W, b, out);
}

// Round 2
// 87.602 us; speedup vs baseline: 1.6482x; 1.6482x over previous
//
#include <hip/hip_runtime.h>
#include <math.h>

#define TWO_PI 6.28318530717958647692f
#define NT     512           // 8 waves per block
#define WPB    8             // waves per block
#define RPW    8             // batched transforms per wave (64 / WPB)
#define PITCH  65            // LDS pitch (+1 pad -> conflict-free transpose)
#define THRESH 10.0f

__device__ __forceinline__ int brev6(int x) {
    return (int)(__brev((unsigned)x) >> 26);
}

// (dr,di) += (ar,ai)*(br,bi)
__device__ __forceinline__ void cfma(float& dr, float& di, float ar, float ai,
                                     float br, float bi) {
    dr = fmaf(ar, br, fmaf(-ai, bi, dr));
    di = fmaf(ar, bi, fmaf(ai, br, di));
}

// Cross-lane 64-pt DIF FFT (radix-2). Natural-order input across lanes;
// output: lane l holds coefficient brev6(l). sign=-1 fwd, +1 inverse(unnorm).
__device__ __forceinline__ void fft64_dif(float (&re)[RPW], float (&im)[RPW],
                                          int lane, float sign) {
    #pragma unroll
    for (int h = 32; h >= 1; h >>= 1) {
        int j = lane & (h - 1);
        float ang = sign * (TWO_PI / 64.0f) * (float)(j * (32 / h));
        float wr, wi;
        __sincosf(ang, &wi, &wr);
        bool upper = (lane & h) != 0;
        float cwr = upper ? wr : 1.0f;
        float cwi = upper ? wi : 0.0f;
        float sgn = upper ? -1.0f : 1.0f;
        #pragma unroll
        for (int m = 0; m < RPW; ++m) {
            float orr = __shfl_xor(re[m], h, 64);
            float oii = __shfl_xor(im[m], h, 64);
            float ar = fmaf(sgn, re[m], orr);   // lower: a+b ; upper: a-b
            float ai = fmaf(sgn, im[m], oii);
            re[m] = ar * cwr - ai * cwi;        // upper gets *w, lower *1
            im[m] = ar * cwi + ai * cwr;
        }
    }
}

// Cross-lane 64-pt DIT FFT. Input bit-reversed across lanes (lane l holds
// element brev6(l)); natural-order output. sign=+1 inverse (unnormalized).
__device__ __forceinline__ void fft64_dit(float (&re)[RPW], float (&im)[RPW],
                                          int lane, float sign) {
    #pragma unroll
    for (int h = 1; h <= 32; h <<= 1) {
        int j = lane & (h - 1);
        float ang = sign * (TWO_PI / 64.0f) * (float)(j * (32 / h));
        float wr, wi;
        __sincosf(ang, &wi, &wr);
        bool upper = (lane & h) != 0;
        float cwr = upper ? wr : 1.0f;
        float cwi = upper ? wi : 0.0f;
        float sgn = upper ? -1.0f : 1.0f;
        #pragma unroll
        for (int m = 0; m < RPW; ++m) {
            float tr = re[m] * cwr - im[m] * cwi;  // upper pre-multiplies by w
            float ti = re[m] * cwi + im[m] * cwr;
            float orr = __shfl_xor(tr, h, 64);
            float oii = __shfl_xor(ti, h, 64);
            re[m] = fmaf(sgn, tr, orr);            // lower: u+t ; upper: u-t
            im[m] = fmaf(sgn, ti, oii);
        }
    }
}

// Kernel 1: per (t,c): pad 62x62 -> 64x64, forward FFT4096 via four-step,
// threshold, store spectrum in lane-permuted layout p = k1*64 + l, where the
// stored value is X[k1 + 64*brev6(l)].
__global__ __launch_bounds__(NT) void fwd_kernel(const float* __restrict__ x,
                                                 float2* __restrict__ X) {
    __shared__ float sre[64 * PITCH];
    __shared__ float sim[64 * PITCH];
    const int tc   = blockIdx.x;
    const int tid  = threadIdx.x;
    const int lane = tid & 63;
    const int w    = tid >> 6;
    const float* xrow = x + (size_t)tc * 62 * 62;

    // Stage padded input row-major into LDS (coalesced, conflict-free).
    for (int idx = tid; idx < 4096; idx += NT) {
        int r = idx >> 6, s = idx & 63;
        float v = 0.0f;
        if (r >= 1 && r <= 62 && s >= 1 && s <= 62)
            v = xrow[(r - 1) * 62 + (s - 1)];
        sre[r * PITCH + s] = v;
    }
    __syncthreads();

    float re[RPW], im[RPW];
    // Phase A: FFT over n1 (lane = n1), columns n2 = w*RPW + m.
    #pragma unroll
    for (int m = 0; m < RPW; ++m) {
        re[m] = sre[lane * PITCH + (w * RPW + m)];
        im[m] = 0.0f;
    }
    fft64_dif(re, im, lane, -1.0f);
    const int k1 = brev6(lane);
    // Mid twiddle: * e^{-2pi i k1 n2 / 4096}
    #pragma unroll
    for (int m = 0; m < RPW; ++m) {
        int n2 = w * RPW + m;
        float cr, ci;
        __sincosf(-(TWO_PI / 4096.0f) * (float)(k1 * n2), &ci, &cr);
        float rr = re[m] * cr - im[m] * ci;
        im[m]    = re[m] * ci + im[m] * cr;
        re[m]    = rr;
    }
    __syncthreads();   // all phase-A LDS reads done before transpose overwrite
    #pragma unroll
    for (int m = 0; m < RPW; ++m) {
        int n2 = w * RPW + m;
        sre[k1 * PITCH + n2] = re[m];
        sim[k1 * PITCH + n2] = im[m];
    }
    __syncthreads();
    // Phase B: FFT over n2 (lane = n2), rows k1 = w*RPW + m.
    #pragma unroll
    for (int m = 0; m < RPW; ++m) {
        int row = w * RPW + m;
        re[m] = sre[row * PITCH + lane];
        im[m] = sim[row * PITCH + lane];
    }
    fft64_dif(re, im, lane, -1.0f);
    // Threshold + store (coalesced, permuted layout).
    float2* Xrow = X + (size_t)tc * 4096;
    #pragma unroll
    for (int m = 0; m < RPW; ++m) {
        int row = w * RPW + m;
        float rr = re[m], ii = im[m];
        if (fabsf(rr) < THRESH) { rr = 0.0f; ii = 0.0f; }
        Xrow[row * 64 + lane] = make_float2(rr, ii);
    }
}

// Kernel 2: per (t,o): S[k] = sum_c X * conj(Wf) built analytically from the
// 9 taps (double-Horner), inverse four-step FFT, crop + bias.
__global__ __launch_bounds__(NT) void conv_kernel(const float2* __restrict__ X,
                                                  const float* __restrict__ W,
                                                  const float* __restrict__ b,
                                                  float* __restrict__ out) {
    __shared__ float sre[64 * PITCH];
    __shared__ float sim[64 * PITCH];
    __shared__ float Wsh[144];
    const int t    = blockIdx.x >> 5;
    const int o    = blockIdx.x & 31;
    const int tid  = threadIdx.x;
    const int lane = tid & 63;
    const int w    = tid >> 6;
    if (tid < 144) Wsh[tid] = W[o * 144 + tid];
    __syncthreads();

    const int k2 = brev6(lane);
    float elr, eli;          // e^{+2pi i k2/64}
    __sincosf((TWO_PI / 64.0f) * (float)k2, &eli, &elr);

    float re[RPW], im[RPW];
    const float2* Xt = X + (size_t)t * 16 * 4096;
    #pragma unroll
    for (int m = 0; m < RPW; ++m) {
        const int k1 = w * RPW + m;          // true k = k1 + 64*k2
        // u = e^{2pi i k1/64} (lane-uniform), v = e^{2pi i k/4096}
        float ur, ui, vkr, vki;
        __sincosf((TWO_PI / 64.0f) * (float)k1, &ui, &ur);
        __sincosf((TWO_PI / 4096.0f) * (float)k1, &vki, &vkr);
        float vr = vkr * elr - vki * eli;
        float vi = vkr * eli + vki * elr;
        // Q_{ij} = sum_c W[c,i,j] * X[c,k]   (tap index q = i*3+j)
        float qr[9] = {0,0,0,0,0,0,0,0,0};
        float qi[9] = {0,0,0,0,0,0,0,0,0};
        const int p = k1 * 64 + lane;
        #pragma unroll
        for (int c = 0; c < 16; ++c) {
            float2 xc = Xt[c * 4096 + p];
            const float* wc = &Wsh[c * 9];
            #pragma unroll
            for (int q = 0; q < 9; ++q) {
                qr[q] = fmaf(wc[q], xc.x, qr[q]);
                qi[q] = fmaf(wc[q], xc.y, qi[q]);
            }
        }
        // S = sum_i u^i (Q_{i0} + v*(Q_{i1} + v*Q_{i2}))  (double Horner)
        float R0r, R0i, R1r, R1i, R2r, R2i, tr_, ti_;
        tr_ = qr[2]; ti_ = qi[2];
        R0r = qr[1]; R0i = qi[1]; cfma(R0r, R0i, vr, vi, tr_, ti_);
        tr_ = R0r; ti_ = R0i;
        R0r = qr[0]; R0i = qi[0]; cfma(R0r, R0i, vr, vi, tr_, ti_);
        tr_ = qr[5]; ti_ = qi[5];
        R1r = qr[4]; R1i = qi[4]; cfma(R1r, R1i, vr, vi, tr_, ti_);
        tr_ = R1r; ti_ = R1i;
        R1r = qr[3]; R1i = qi[3]; cfma(R1r, R1i, vr, vi, tr_, ti_);
        tr_ = qr[8]; ti_ = qi[8];
        R2r = qr[7]; R2i = qi[7]; cfma(R2r, R2i, vr, vi, tr_, ti_);
        tr_ = R2r; ti_ = R2i;
        R2r = qr[6]; R2i = qi[6]; cfma(R2r, R2i, vr, vi, tr_, ti_);
        // S = R0 + u*(R1 + u*R2)
        cfma(R1r, R1i, ur, ui, R2r, R2i);
        cfma(R0r, R0i, ur, ui, R1r, R1i);
        re[m] = R0r;
        im[m] = R0i;
    }
    // Phase 1: inverse FFT over k2 (lanes hold k2 = brev6(l) -> DIT).
    fft64_dit(re, im, lane, +1.0f);
    // Mid twiddle: * e^{+2pi i n2 k1 / 4096}, n2 = lane.
    #pragma unroll
    for (int m = 0; m < RPW; ++m) {
        int k1 = w * RPW + m;
        float cr, ci;
        __sincosf((TWO_PI / 4096.0f) * (float)(k1 * lane), &ci, &cr);
        float rr = re[m] * cr - im[m] * ci;
        im[m]    = re[m] * ci + im[m] * cr;
        re[m]    = rr;
    }
    // Transpose through LDS: write [k1][n2].
    #pragma unroll
    for (int m = 0; m < RPW; ++m) {
        int k1 = w * RPW + m;
        sre[k1 * PITCH + lane] = re[m];
        sim[k1 * PITCH + lane] = im[m];
    }
    __syncthreads();
    // Phase 2: inverse FFT over k1 (lane = k1), columns n2 = w*RPW + m.
    #pragma unroll
    for (int m = 0; m < RPW; ++m) {
        int n2 = w * RPW + m;
        re[m] = sre[lane * PITCH + n2];
        im[m] = sim[lane * PITCH + n2];
    }
    fft64_dif(re, im, lane, +1.0f);
    __syncthreads();   // phase-2 reads done before y overwrite
    // Lane l holds y[n1 = brev6(l)][n2]; unscramble via LDS for coalesced store.
    const int n1 = brev6(lane);
    #pragma unroll
    for (int m = 0; m < RPW; ++m) {
        int n2 = w * RPW + m;
        sre[n1 * PITCH + n2] = re[m];
    }
    __syncthreads();
    const float bias = b[o];
    float* orow = out + (size_t)blockIdx.x * 62 * 62;
    for (int idx = tid; idx < 62 * 62; idx += NT) {
        int r = idx / 62, s = idx - r * 62;
        orow[idx] = sre[r * PITCH + s] * (1.0f / 4096.0f) + bias;
    }
}

extern "C" void kernel_launch(void* const* d_in, const int* in_sizes, int n_in,
                              void* d_out, int out_size, void* d_ws, size_t ws_size,
                              hipStream_t stream) {
    const float* x = (const float*)d_in[0];   // (8,16,62,62) f32
    const float* W = (const float*)d_in[1];   // (32,16,3,3)  f32
    const float* b = (const float*)d_in[2];   // (32,)        f32
    float* out = (float*)d_out;               // (8,32,62,62) f32
    float2* X = (float2*)d_ws;                // 128*4096 complex = 4 MB

    fwd_kernel<<<dim3(128), dim3(NT), 0, stream>>>(x, X);
    conv_kernel<<<dim3(256), dim3(NT), 0, stream>>>(X, W, b, out);
}